// Round 4
// baseline (586.720 us; speedup 1.0000x reference)
//
#include <hip/hip_runtime.h>

namespace {
constexpr int kB   = 8;
constexpr int kN   = 5000;
constexpr int kE   = 40000;
constexpr int kF   = 64;
constexpr int kFE  = 16;
constexpr int kFil = 96;
constexpr int kDm  = 144;  // 2F + FE
constexpr int kDu  = 160;  // F + FILTERS
constexpr float kEps = 1e-3f;
constexpr int kBN = kB * kN;   // 40000
constexpr int kBE = kB * kE;   // 320000
constexpr int kHalf = kFil / 2;  // 48 outputs per thread
}

// ---------------------------------------------------------------------------
// CSR build: count -> scan -> scatter
// ---------------------------------------------------------------------------
__global__ void count_kernel(const int* __restrict__ edges, int* __restrict__ counts) {
    const int idx = blockIdx.x * 256 + threadIdx.x;
    if (idx >= kBE) return;
    const int b = idx / kE;
    const int dst = edges[(size_t)idx * 2 + 1];
    atomicAdd(&counts[b * kN + dst], 1);
}

__global__ __launch_bounds__(1024) void scan_kernel(const int* __restrict__ counts,
                                                    int* __restrict__ offsets) {
    __shared__ int part[1024];
    const int t = threadIdx.x;
    const int chunk = (kBN + 1023) / 1024;   // 40
    const int base = t * chunk;
    int s = 0;
    for (int i = 0; i < chunk; ++i) {
        const int j = base + i;
        if (j < kBN) s += counts[j];
    }
    part[t] = s;
    __syncthreads();
    for (int d = 1; d < 1024; d <<= 1) {
        const int v = (t >= d) ? part[t - d] : 0;
        __syncthreads();
        part[t] += v;
        __syncthreads();
    }
    int run = part[t] - s;   // exclusive prefix
    for (int i = 0; i < chunk; ++i) {
        const int j = base + i;
        if (j < kBN) {
            offsets[j] = run;
            run += counts[j];
        }
    }
}

__global__ void scatter_kernel(const int* __restrict__ edges,
                               const int* __restrict__ offsets,
                               int* __restrict__ cursor,
                               int* __restrict__ edge_ids) {
    const int idx = blockIdx.x * 256 + threadIdx.x;
    if (idx >= kBE) return;
    const int b = idx / kE;
    const int dst = edges[(size_t)idx * 2 + 1];
    const int node = b * kN + dst;
    const int pos = offsets[node] + atomicAdd(&cursor[node], 1);
    edge_ids[pos] = idx;
}

// ---------------------------------------------------------------------------
// Message kernel, round 4: weights via wave-uniform s_load (SGPR broadcast).
// Wave pairs (2k,2k+1) cover the same 64 edges; h = wave parity selects the
// 48-col half. hc is readfirstlane-forced uniform so Wm reads scalarize to
// s_load_dwordx16 + v_fmac(v,s,v) — zero LDS weight traffic (round 3 was
// LDS-return-BW bound: 27.6KB/thread * 640k = 17.7GB -> 225us floor).
// LDS now only exchanges LN partial sums between paired waves (4KB).
// ---------------------------------------------------------------------------
__global__ __launch_bounds__(512) void gnn_msg_kernel(
    const float* __restrict__ nodes,   // (B,N,F)
    const float* __restrict__ efeat,   // (B,E,FE)
    const int*   __restrict__ edges,   // (B,E,2)
    const float* __restrict__ Wm,      // (144,96)
    const float* __restrict__ bm,      // (96)
    const float* __restrict__ gamma_,  // (96)
    const float* __restrict__ beta_,   // (96)
    float* __restrict__ out_msg)       // (B,E,96)
{
    __shared__ float sS[512];
    __shared__ float sV[512];

    const int tid  = threadIdx.x;
    const int lane = tid & 63;
    const int wv   = tid >> 6;     // 0..7
    const int pair = wv >> 1;      // 0..3
    const int h    = wv & 1;
    const int hc   = __builtin_amdgcn_readfirstlane(h * kHalf);

    const int edge = blockIdx.x * 256 + pair * 64 + lane;  // 1250*256 = 320000 exact
    const int b    = edge / kE;

    const int src = edges[(size_t)edge * 2 + 0];
    const int dst = edges[(size_t)edge * 2 + 1];

    const float* srow = nodes + ((size_t)b * kN + src) * kF;
    const float* drow = nodes + ((size_t)b * kN + dst) * kF;
    const float* erow = efeat + (size_t)edge * kFE;

    float acc[kHalf];
#pragma unroll
    for (int f = 0; f < kHalf; ++f) acc[f] = bm[hc + f];   // uniform -> s_load

    // 9 chunks of 16 inputs: 0..3 src row, 4..7 dst row, 8 edge feats
#pragma unroll 1
    for (int kc = 0; kc < 9; ++kc) {
        const float* bptr;
        if (kc < 4)      bptr = srow + kc * 16;
        else if (kc < 8) bptr = drow + (kc - 4) * 16;
        else             bptr = erow;
        const float4* p4 = reinterpret_cast<const float4*>(bptr);
        float4 x0 = p4[0], x1 = p4[1], x2 = p4[2], x3 = p4[3];
        float xin[16] = {x0.x, x0.y, x0.z, x0.w, x1.x, x1.y, x1.z, x1.w,
                         x2.x, x2.y, x2.z, x2.w, x3.x, x3.y, x3.z, x3.w};
#pragma unroll
        for (int kk = 0; kk < 16; ++kk) {
            const float x = xin[kk];
            const float* wrow = Wm + (size_t)(kc * 16 + kk) * kFil + hc;  // uniform
#pragma unroll
            for (int f = 0; f < kHalf; ++f)
                acc[f] = fmaf(x, wrow[f], acc[f]);
        }
    }

    // ReLU + LN; stats combined across the paired wave via LDS
    float s = 0.f;
#pragma unroll
    for (int f = 0; f < kHalf; ++f) {
        acc[f] = fmaxf(acc[f], 0.f);
        s += acc[f];
    }
    sS[tid] = s;
    __syncthreads();
    s = sS[tid] + sS[tid ^ 64];
    const float mu = s * (1.0f / kFil);
    float v = 0.f;
#pragma unroll
    for (int f = 0; f < kHalf; ++f) {
        const float d = acc[f] - mu;
        v = fmaf(d, d, v);
    }
    sV[tid] = v;
    __syncthreads();
    v = sV[tid] + sV[tid ^ 64];
    const float inv = rsqrtf(v * (1.0f / kFil) + kEps);
#pragma unroll
    for (int f = 0; f < kHalf; ++f)
        acc[f] = (acc[f] - mu) * inv * gamma_[hc + f] + beta_[hc + f];

    float* mrow = out_msg + (size_t)edge * kFil + hc;   // 192B, 64B-aligned
#pragma unroll
    for (int f = 0; f < kHalf; f += 4) {
        float4 o = {acc[f], acc[f + 1], acc[f + 2], acc[f + 3]};
        *reinterpret_cast<float4*>(mrow + f) = o;
    }
}

// ---------------------------------------------------------------------------
// Aggregate: one wave per node; lanes = 24 col-chunks x 2 edge-parity.
// ---------------------------------------------------------------------------
__global__ __launch_bounds__(256) void agg_kernel(
    const float* __restrict__ msg,        // (B,E,96)
    const int*   __restrict__ offsets,    // (B*N)
    const int*   __restrict__ counts,     // (B*N)
    const int*   __restrict__ edge_ids,   // (B*E)
    float* __restrict__ agg)              // (B,N,96)
{
    const int wave = threadIdx.x >> 6;
    const int lane = threadIdx.x & 63;
    const int node = blockIdx.x * 4 + wave;
    if (node >= kBN) return;
    const int start = offsets[node];
    const int cnt   = counts[node];
    const int p = lane >> 5;      // edge parity
    const int c = lane & 31;      // float4 column chunk (0..23 active)
    float4 acc = {0.f, 0.f, 0.f, 0.f};
    if (c < 24) {
        for (int e = p; e < cnt; e += 2) {
            const int eid = edge_ids[start + e];
            const float4 x =
                reinterpret_cast<const float4*>(msg + (size_t)eid * kFil)[c];
            acc.x += x.x; acc.y += x.y; acc.z += x.z; acc.w += x.w;
        }
    }
    acc.x += __shfl_xor(acc.x, 32);
    acc.y += __shfl_xor(acc.y, 32);
    acc.z += __shfl_xor(acc.z, 32);
    acc.w += __shfl_xor(acc.w, 32);
    if (p == 0 && c < 24)
        reinterpret_cast<float4*>(agg + (size_t)node * kFil)[c] = acc;
}

// ---------------------------------------------------------------------------
// Update kernel: same SGPR-weight structure; guarded (40000 not /256).
// No early returns (barriers must be uniform).
// ---------------------------------------------------------------------------
__global__ __launch_bounds__(512) void gnn_upd_kernel(
    const float* __restrict__ nodes,   // (B,N,F)
    const float* __restrict__ agg,     // (B,N,96)
    const float* __restrict__ Wu,      // (160,96)
    const float* __restrict__ bu,      // (96)
    const float* __restrict__ gamma_,  // (96)
    const float* __restrict__ beta_,   // (96)
    float* __restrict__ out_upd)       // (B,N,96)
{
    __shared__ float sS[512];
    __shared__ float sV[512];

    const int tid  = threadIdx.x;
    const int lane = tid & 63;
    const int wv   = tid >> 6;
    const int pair = wv >> 1;
    const int h    = wv & 1;
    const int hc   = __builtin_amdgcn_readfirstlane(h * kHalf);

    const int node = blockIdx.x * 256 + pair * 64 + lane;
    const bool ok  = node < kBN;

    const float* srow = nodes + (size_t)(ok ? node : 0) * kF;
    const float* arow = agg + (size_t)(ok ? node : 0) * kFil;

    float acc[kHalf];
#pragma unroll
    for (int f = 0; f < kHalf; ++f) acc[f] = bu[hc + f];

#pragma unroll 1
    for (int kc = 0; kc < 10; ++kc) {
        const float* bptr;
        if (kc < 4) bptr = srow + kc * 16;
        else        bptr = arow + (kc - 4) * 16;
        const float4* p4 = reinterpret_cast<const float4*>(bptr);
        float4 x0 = p4[0], x1 = p4[1], x2 = p4[2], x3 = p4[3];
        float xin[16] = {x0.x, x0.y, x0.z, x0.w, x1.x, x1.y, x1.z, x1.w,
                         x2.x, x2.y, x2.z, x2.w, x3.x, x3.y, x3.z, x3.w};
#pragma unroll
        for (int kk = 0; kk < 16; ++kk) {
            const float x = xin[kk];
            const float* wrow = Wu + (size_t)(kc * 16 + kk) * kFil + hc;  // uniform
#pragma unroll
            for (int f = 0; f < kHalf; ++f)
                acc[f] = fmaf(x, wrow[f], acc[f]);
        }
    }

    float s = 0.f;
#pragma unroll
    for (int f = 0; f < kHalf; ++f) {
        acc[f] = fmaxf(acc[f], 0.f);
        s += acc[f];
    }
    sS[tid] = s;
    __syncthreads();
    s = sS[tid] + sS[tid ^ 64];
    const float mu = s * (1.0f / kFil);
    float v = 0.f;
#pragma unroll
    for (int f = 0; f < kHalf; ++f) {
        const float d = acc[f] - mu;
        v = fmaf(d, d, v);
    }
    sV[tid] = v;
    __syncthreads();
    v = sV[tid] + sV[tid ^ 64];
    const float inv = rsqrtf(v * (1.0f / kFil) + kEps);
#pragma unroll
    for (int f = 0; f < kHalf; ++f)
        acc[f] = (acc[f] - mu) * inv * gamma_[hc + f] + beta_[hc + f];

    if (ok) {
        float* orow = out_upd + (size_t)node * kFil + hc;
#pragma unroll
        for (int f = 0; f < kHalf; f += 4) {
            float4 o = {acc[f], acc[f + 1], acc[f + 2], acc[f + 3]};
            *reinterpret_cast<float4*>(orow + f) = o;
        }
    }
}

extern "C" void kernel_launch(void* const* d_in, const int* in_sizes, int n_in,
                              void* d_out, int out_size, void* d_ws, size_t ws_size,
                              hipStream_t stream) {
    const float* nodes  = (const float*)d_in[0];
    const float* efeat  = (const float*)d_in[1];
    const int*   edges  = (const int*)d_in[2];
    const float* Wm     = (const float*)d_in[3];
    const float* bm     = (const float*)d_in[4];
    const float* ln_m_g = (const float*)d_in[5];
    const float* ln_m_b = (const float*)d_in[6];
    const float* Wu     = (const float*)d_in[7];
    const float* bu     = (const float*)d_in[8];
    const float* ln_u_g = (const float*)d_in[9];
    const float* ln_u_b = (const float*)d_in[10];

    float* out_upd = (float*)d_out;                           // (B,N,96) first
    float* out_msg = (float*)d_out + (size_t)kBN * kFil;      // (B,E,96) second

    // workspace layout (~17.1 MB)
    float* agg      = (float*)d_ws;                           // B*N*96 floats
    int*   counts   = (int*)(agg + (size_t)kBN * kFil);       // 40000
    int*   cursor   = counts + kBN;                           // 40000
    int*   offsets  = cursor + kBN;                           // 40000
    int*   edge_ids = offsets + kBN;                          // 320000

    hipMemsetAsync(counts, 0, (size_t)2 * kBN * sizeof(int), stream);

    count_kernel<<<(kBE + 255) / 256, 256, 0, stream>>>(edges, counts);
    scan_kernel<<<1, 1024, 0, stream>>>(counts, offsets);
    scatter_kernel<<<(kBE + 255) / 256, 256, 0, stream>>>(edges, offsets, cursor, edge_ids);

    gnn_msg_kernel<<<kBE / 256, 512, 0, stream>>>(
        nodes, efeat, edges, Wm, bm, ln_m_g, ln_m_b, out_msg);
    agg_kernel<<<(kBN + 3) / 4, 256, 0, stream>>>(
        out_msg, offsets, counts, edge_ids, agg);
    gnn_upd_kernel<<<(kBN + 255) / 256, 512, 0, stream>>>(
        nodes, agg, Wu, bu, ln_u_g, ln_u_b, out_upd);
}

// Round 5
// 360.300 us; speedup vs baseline: 1.6284x; 1.6284x over previous
//
#include <hip/hip_runtime.h>

typedef short s16x8 __attribute__((ext_vector_type(8)));
typedef float f32x4 __attribute__((ext_vector_type(4)));

namespace {
constexpr int kB   = 8;
constexpr int kN   = 5000;
constexpr int kE   = 40000;
constexpr int kF   = 64;
constexpr int kFE  = 16;
constexpr int kFil = 96;
constexpr float kEps = 1e-3f;
constexpr int kBN = kB * kN;   // 40000
constexpr int kBE = kB * kE;   // 320000
constexpr int kKp = 160;       // padded K (msg 144->160, upd exact 160)
constexpr int kLd = 168;       // LDS row stride in bf16 elems (bank decorrelation)
constexpr int kBM = 128;       // rows per block
}

// float -> bf16 (RNE) without relying on __bf16 types
__device__ inline unsigned short f2bf(float x) {
    unsigned u = __float_as_uint(x);
    u += 0x7FFFu + ((u >> 16) & 1u);
    return (unsigned short)(u >> 16);
}

__device__ inline s16x8 pack8(const float4& a, const float4& b) {
    s16x8 r;
    r[0] = (short)f2bf(a.x); r[1] = (short)f2bf(a.y);
    r[2] = (short)f2bf(a.z); r[3] = (short)f2bf(a.w);
    r[4] = (short)f2bf(b.x); r[5] = (short)f2bf(b.y);
    r[6] = (short)f2bf(b.z); r[7] = (short)f2bf(b.w);
    return r;
}

// ---------------------------------------------------------------------------
// Prep: W (K,96) fp32 -> WT (96,Kp) bf16, zero-padded K rows. Runs once/call.
// ---------------------------------------------------------------------------
__global__ void prep_wT(const float* __restrict__ Wm, const float* __restrict__ Wu,
                        short* __restrict__ wmT, short* __restrict__ wuT) {
    const int t = blockIdx.x * 256 + threadIdx.x;
    if (t >= 96 * kKp) return;
    const int n = t / kKp, k = t % kKp;
    wmT[t] = (k < 144) ? (short)f2bf(Wm[(size_t)k * 96 + n]) : (short)0;
    wuT[t] = (short)f2bf(Wu[(size_t)k * 96 + n]);
}

// ---------------------------------------------------------------------------
// CSR build: count -> scan -> scatter (unchanged, proven)
// ---------------------------------------------------------------------------
__global__ void count_kernel(const int* __restrict__ edges, int* __restrict__ counts) {
    const int idx = blockIdx.x * 256 + threadIdx.x;
    if (idx >= kBE) return;
    const int b = idx / kE;
    const int dst = edges[(size_t)idx * 2 + 1];
    atomicAdd(&counts[b * kN + dst], 1);
}

__global__ __launch_bounds__(1024) void scan_kernel(const int* __restrict__ counts,
                                                    int* __restrict__ offsets) {
    __shared__ int part[1024];
    const int t = threadIdx.x;
    const int chunk = (kBN + 1023) / 1024;   // 40
    const int base = t * chunk;
    int s = 0;
    for (int i = 0; i < chunk; ++i) {
        const int j = base + i;
        if (j < kBN) s += counts[j];
    }
    part[t] = s;
    __syncthreads();
    for (int d = 1; d < 1024; d <<= 1) {
        const int v = (t >= d) ? part[t - d] : 0;
        __syncthreads();
        part[t] += v;
        __syncthreads();
    }
    int run = part[t] - s;   // exclusive prefix
    for (int i = 0; i < chunk; ++i) {
        const int j = base + i;
        if (j < kBN) {
            offsets[j] = run;
            run += counts[j];
        }
    }
}

__global__ void scatter_kernel(const int* __restrict__ edges,
                               const int* __restrict__ offsets,
                               int* __restrict__ cursor,
                               int* __restrict__ edge_ids) {
    const int idx = blockIdx.x * 256 + threadIdx.x;
    if (idx >= kBE) return;
    const int b = idx / kE;
    const int dst = edges[(size_t)idx * 2 + 1];
    const int node = b * kN + dst;
    const int pos = offsets[node] + atomicAdd(&cursor[node], 1);
    edge_ids[pos] = idx;
}

// ---------------------------------------------------------------------------
// Shared MFMA GEMM (128xKp @ Kpx96) + fp32 bias/ReLU/LN epilogue + store.
// A-frag: A[m=lane&15][k=quad*8+j]; B-frag: B[k=quad*8+j][n=lane&15];
// C/D: col=lane&15, row=quad*4+reg  [per guide §3, HW-verified mappings].
// LN: row lives in one 16-lane quad across 6 N-tiles -> shfl_xor(1,2,4,8).
// ---------------------------------------------------------------------------
__device__ inline void gemm_ln_store(const short* sX, const short* sB,
                                     const float* __restrict__ bias,
                                     const float* __restrict__ gamma_,
                                     const float* __restrict__ beta_,
                                     float* __restrict__ out,
                                     int rowBase, int rowMax) {
    const int tid  = threadIdx.x;
    const int w    = tid >> 6;
    const int lane = tid & 63;
    const int cl   = lane & 15;
    const int quad = lane >> 4;

    f32x4 acc[6] = {};
    const short* aBase = sX + (16 * w + cl) * kLd + quad * 8;
#pragma unroll
    for (int ks = 0; ks < 5; ++ks) {
        s16x8 a = *reinterpret_cast<const s16x8*>(aBase + ks * 32);
#pragma unroll
        for (int t = 0; t < 6; ++t) {
            s16x8 b = *reinterpret_cast<const s16x8*>(
                sB + (16 * t + cl) * kLd + ks * 32 + quad * 8);
            acc[t] = __builtin_amdgcn_mfma_f32_16x16x32_bf16(a, b, acc[t], 0, 0, 0);
        }
    }

    float bmv[6], gv[6], bv[6];
#pragma unroll
    for (int t = 0; t < 6; ++t) {
        const int c = 16 * t + cl;
        bmv[t] = bias[c]; gv[t] = gamma_[c]; bv[t] = beta_[c];
    }
#pragma unroll
    for (int j = 0; j < 4; ++j) {
        float v0[6];
        float s = 0.f;
#pragma unroll
        for (int t = 0; t < 6; ++t) {
            v0[t] = fmaxf(acc[t][j] + bmv[t], 0.f);
            s += v0[t];
        }
        s += __shfl_xor(s, 1); s += __shfl_xor(s, 2);
        s += __shfl_xor(s, 4); s += __shfl_xor(s, 8);
        const float mu = s * (1.f / 96.f);
        float q = 0.f;
#pragma unroll
        for (int t = 0; t < 6; ++t) {
            const float d = v0[t] - mu;
            q = fmaf(d, d, q);
        }
        q += __shfl_xor(q, 1); q += __shfl_xor(q, 2);
        q += __shfl_xor(q, 4); q += __shfl_xor(q, 8);
        const float inv = rsqrtf(q * (1.f / 96.f) + kEps);
        const int row = rowBase + 16 * w + 4 * quad + j;
        if (row < rowMax) {
            float* orow = out + (size_t)row * kFil;
#pragma unroll
            for (int t = 0; t < 6; ++t)
                orow[16 * t + cl] = (v0[t] - mu) * inv * gv[t] + bv[t];
        }
    }
}

// ---------------------------------------------------------------------------
// Message layer (MFMA): block = 128 edges. Threads 0..255 gather/stage X rows
// [src(64)|dst(64)|efeat(16)|zeros(16)] as bf16; threads 256..511 stage WT.
// ---------------------------------------------------------------------------
__global__ __launch_bounds__(512) void msg_mfma(
    const float* __restrict__ nodes, const float* __restrict__ efeat,
    const int* __restrict__ edges, const short* __restrict__ wmT,
    const float* __restrict__ bm, const float* __restrict__ g,
    const float* __restrict__ be, float* __restrict__ out_msg) {
    __shared__ short sX[kBM * kLd];   // 43008 B
    __shared__ short sB[96 * kLd];    // 32256 B
    const int tid = threadIdx.x;
    if (tid < 256) {
        const int r = tid >> 1, half = tid & 1;
        const int edge = blockIdx.x * kBM + r;     // 2500*128 = 320000 exact
        const int b = edge / kE;
        short* dstRow = sX + r * kLd;
        if (half == 0) {
            const int s = edges[(size_t)edge * 2];
            const float4* p = reinterpret_cast<const float4*>(
                nodes + ((size_t)b * kN + s) * kF);
#pragma unroll
            for (int c = 0; c < 8; ++c)
                *reinterpret_cast<s16x8*>(dstRow + 8 * c) = pack8(p[2 * c], p[2 * c + 1]);
        } else {
            const int d = edges[(size_t)edge * 2 + 1];
            const float4* p = reinterpret_cast<const float4*>(
                nodes + ((size_t)b * kN + d) * kF);
#pragma unroll
            for (int c = 0; c < 8; ++c)
                *reinterpret_cast<s16x8*>(dstRow + 64 + 8 * c) = pack8(p[2 * c], p[2 * c + 1]);
            const float4* pe = reinterpret_cast<const float4*>(efeat + (size_t)edge * kFE);
#pragma unroll
            for (int c = 0; c < 2; ++c)
                *reinterpret_cast<s16x8*>(dstRow + 128 + 8 * c) = pack8(pe[2 * c], pe[2 * c + 1]);
            s16x8 z = {};
            *reinterpret_cast<s16x8*>(dstRow + 144) = z;   // zero-pad K 144..159
            *reinterpret_cast<s16x8*>(dstRow + 152) = z;
        }
    } else {
        for (int i = tid - 256; i < 96 * kKp / 8; i += 256) {   // 1920 16B chunks
            const int n = i / 20, c = i % 20;
            *reinterpret_cast<s16x8*>(sB + n * kLd + 8 * c) =
                *reinterpret_cast<const s16x8*>(wmT + n * kKp + 8 * c);
        }
    }
    __syncthreads();
    gemm_ln_store(sX, sB, bm, g, be, out_msg, blockIdx.x * kBM, kBE);
}

// ---------------------------------------------------------------------------
// Update layer (MFMA): block = 128 nodes; X row = [node(64)|agg(96)], K=160.
// ---------------------------------------------------------------------------
__global__ __launch_bounds__(512) void upd_mfma(
    const float* __restrict__ nodes, const float* __restrict__ agg,
    const short* __restrict__ wuT, const float* __restrict__ bu,
    const float* __restrict__ g, const float* __restrict__ be,
    float* __restrict__ out_upd) {
    __shared__ short sX[kBM * kLd];
    __shared__ short sB[96 * kLd];
    const int tid = threadIdx.x;
    if (tid < 256) {
        const int r = tid >> 1, half = tid & 1;
        const int node = blockIdx.x * kBM + r;
        const bool ok = node < kBN;
        short* dstRow = sX + r * kLd;
        const s16x8 z = {};
        if (half == 0) {
            const float4* p = reinterpret_cast<const float4*>(
                nodes + (size_t)(ok ? node : 0) * kF);
#pragma unroll
            for (int c = 0; c < 8; ++c)
                *reinterpret_cast<s16x8*>(dstRow + 8 * c) =
                    ok ? pack8(p[2 * c], p[2 * c + 1]) : z;
        } else {
            const float4* p = reinterpret_cast<const float4*>(
                agg + (size_t)(ok ? node : 0) * kFil);
#pragma unroll
            for (int c = 0; c < 12; ++c)
                *reinterpret_cast<s16x8*>(dstRow + 64 + 8 * c) =
                    ok ? pack8(p[2 * c], p[2 * c + 1]) : z;
        }
    } else {
        for (int i = tid - 256; i < 96 * kKp / 8; i += 256) {
            const int n = i / 20, c = i % 20;
            *reinterpret_cast<s16x8*>(sB + n * kLd + 8 * c) =
                *reinterpret_cast<const s16x8*>(wuT + n * kKp + 8 * c);
        }
    }
    __syncthreads();
    gemm_ln_store(sX, sB, bu, g, be, out_upd, blockIdx.x * kBM, kBN);
}

// ---------------------------------------------------------------------------
// Aggregate: one wave per node; lanes = 24 col-chunks x 2 edge-parity.
// ---------------------------------------------------------------------------
__global__ __launch_bounds__(256) void agg_kernel(
    const float* __restrict__ msg,        // (B,E,96)
    const int*   __restrict__ offsets,    // (B*N)
    const int*   __restrict__ counts,     // (B*N)
    const int*   __restrict__ edge_ids,   // (B*E)
    float* __restrict__ agg)              // (B,N,96)
{
    const int wave = threadIdx.x >> 6;
    const int lane = threadIdx.x & 63;
    const int node = blockIdx.x * 4 + wave;
    if (node >= kBN) return;
    const int start = offsets[node];
    const int cnt   = counts[node];
    const int p = lane >> 5;      // edge parity
    const int c = lane & 31;      // float4 column chunk (0..23 active)
    float4 acc = {0.f, 0.f, 0.f, 0.f};
    if (c < 24) {
        for (int e = p; e < cnt; e += 2) {
            const int eid = edge_ids[start + e];
            const float4 x =
                reinterpret_cast<const float4*>(msg + (size_t)eid * kFil)[c];
            acc.x += x.x; acc.y += x.y; acc.z += x.z; acc.w += x.w;
        }
    }
    acc.x += __shfl_xor(acc.x, 32);
    acc.y += __shfl_xor(acc.y, 32);
    acc.z += __shfl_xor(acc.z, 32);
    acc.w += __shfl_xor(acc.w, 32);
    if (p == 0 && c < 24)
        reinterpret_cast<float4*>(agg + (size_t)node * kFil)[c] = acc;
}

extern "C" void kernel_launch(void* const* d_in, const int* in_sizes, int n_in,
                              void* d_out, int out_size, void* d_ws, size_t ws_size,
                              hipStream_t stream) {
    const float* nodes  = (const float*)d_in[0];
    const float* efeat  = (const float*)d_in[1];
    const int*   edges  = (const int*)d_in[2];
    const float* Wm     = (const float*)d_in[3];
    const float* bm     = (const float*)d_in[4];
    const float* ln_m_g = (const float*)d_in[5];
    const float* ln_m_b = (const float*)d_in[6];
    const float* Wu     = (const float*)d_in[7];
    const float* bu     = (const float*)d_in[8];
    const float* ln_u_g = (const float*)d_in[9];
    const float* ln_u_b = (const float*)d_in[10];

    float* out_upd = (float*)d_out;                           // (B,N,96) first
    float* out_msg = (float*)d_out + (size_t)kBN * kFil;      // (B,E,96) second

    // workspace layout (~17.2 MB); 16B-aligned segments
    short* wmT      = (short*)d_ws;                           // 96*160 bf16
    short* wuT      = wmT + 96 * kKp;                         // 96*160 bf16
    float* agg      = (float*)(wuT + 96 * kKp);               // B*N*96 floats
    int*   counts   = (int*)(agg + (size_t)kBN * kFil);       // 40000
    int*   cursor   = counts + kBN;                           // 40000
    int*   offsets  = cursor + kBN;                           // 40000
    int*   edge_ids = offsets + kBN;                          // 320000

    hipMemsetAsync(counts, 0, (size_t)2 * kBN * sizeof(int), stream);
    prep_wT<<<(96 * kKp + 255) / 256, 256, 0, stream>>>(Wm, Wu, wmT, wuT);

    count_kernel<<<(kBE + 255) / 256, 256, 0, stream>>>(edges, counts);
    scan_kernel<<<1, 1024, 0, stream>>>(counts, offsets);
    scatter_kernel<<<(kBE + 255) / 256, 256, 0, stream>>>(edges, offsets, cursor, edge_ids);

    msg_mfma<<<kBE / kBM, 512, 0, stream>>>(
        nodes, efeat, edges, wmT, bm, ln_m_g, ln_m_b, out_msg);
    agg_kernel<<<(kBN + 3) / 4, 256, 0, stream>>>(
        out_msg, offsets, counts, edge_ids, agg);
    upd_mfma<<<(kBN + kBM - 1) / kBM, 512, 0, stream>>>(
        nodes, agg, wuT, bu, ln_u_g, ln_u_b, out_upd);
}